// Round 4
// baseline (590.024 us; speedup 1.0000x reference)
//
#include <hip/hip_runtime.h>
#include <math.h>

// Problem constants
#define HID   4096
#define SLOTS 8
#define HEADS 8
#define BD    512
#define HD    64
#define BB    4
#define SS    4096
#define R64   64          // HEADS*SLOTS rows; r = h*8 + n

typedef __attribute__((ext_vector_type(8))) short bf16x8;
typedef __attribute__((ext_vector_type(4))) float f32x4;

// fp32 -> bf16 bits, round-to-nearest-even (inputs finite)
__device__ __forceinline__ unsigned short f2bf(float x) {
  unsigned int u = __builtin_bit_cast(unsigned int, x);
  return (unsigned short)((u + 0x7fffu + ((u >> 16) & 1u)) >> 16);
}

// ---- 0: hs fp32 -> bf16, streaming (memcpy-class). 64M elems, 8 per thread-iter.
__global__ __launch_bounds__(256) void cvt_kernel(const float4* __restrict__ hs,
                                                  uint2* __restrict__ hsbf) {
  const int nthreads = gridDim.x * 256;
  int idx = blockIdx.x * 256 + threadIdx.x;
  const int total = BB * SS * HID / 4;   // float4 count = 16.8M
  for (; idx < total; idx += nthreads) {
    float4 v = hs[idx];
    uint2 o;
    o.x = (unsigned int)f2bf(v.x) | ((unsigned int)f2bf(v.y) << 16);
    o.y = (unsigned int)f2bf(v.z) | ((unsigned int)f2bf(v.w) << 16);
    hsbf[idx] = o;
  }
}

// ---- 1: Q = ms @ Wq^T  (8x512). One wave per output element.
__global__ void q_kernel(const float* __restrict__ ms, const float* __restrict__ Wq,
                         float* __restrict__ Q) {
  int w = (blockIdx.x * blockDim.x + threadIdx.x) >> 6;
  int lane = threadIdx.x & 63;
  if (w >= SLOTS * BD) return;
  int n = w >> 9, o = w & (BD - 1);
  const float* a = ms + n * HID;
  const float* b = Wq + (size_t)o * HID;
  float acc = 0.f;
  for (int i = lane; i < HID; i += 64) acc = fmaf(a[i], b[i], acc);
  #pragma unroll
  for (int off = 32; off; off >>= 1) acc += __shfl_down(acc, off, 64);
  if (lane == 0) Q[w] = acc;
}

// ---- 2: QW[r][i] = 0.125 * sum_d Q[n][h*64+d] * Wk[h*64+d][i],  r = h*8+n  (bf16 out)
__global__ void qw_kernel(const float* __restrict__ Q, const float* __restrict__ Wk,
                          unsigned short* __restrict__ QW) {
  int idx = blockIdx.x * blockDim.x + threadIdx.x;   // 64*4096
  int r = idx >> 12, i = idx & (HID - 1);
  int h = r >> 3, n = r & 7;
  const float* q  = Q + n * BD + h * HD;
  const float* wk = Wk + (size_t)(h * HD) * HID + i;
  float acc = 0.f;
  #pragma unroll 8
  for (int d = 0; d < HD; ++d) acc = fmaf(q[d], wk[(size_t)d * HID], acc);
  QW[idx] = f2bf(acc * 0.125f);
}

// ---- 3: partial scores sp[ks][b][r][s] = sum_{k-slice} hsbf[b][s][k]*QW[r][k]
// A = QW (LDS, swizzled, staged per 256-k chunk from L2-hot global).
// B = hsbf read DIRECTLY from global into B-frags (row-major [s][k] == B-frag layout):
//   lane: n=s0+l16, k=quad*8.. -> one dwordx4 per ksub; 8 in flight per chunk; no barriers.
// grid (64 stile, 4 ks, 4 b), 256 thr. Output 64r x 64s per block, K-slice 1024.
__global__ __launch_bounds__(256, 4) void scores_mfma(const unsigned short* __restrict__ hsbf,
                                                      const unsigned short* __restrict__ QW,
                                                      float* __restrict__ sp) {
  __shared__ unsigned short Qs[64 * 256];  // 32 KB: [r][k-chunk] 16B-chunk XOR-swizzled
  const int stile = blockIdx.x, ks = blockIdx.y, b = blockIdx.z;
  const int tid = threadIdx.x;
  const int wv = tid >> 6, lane = tid & 63;
  const int quad = lane >> 4, l16 = lane & 15;
  // QW staging map: row = tid>>2 (4 threads/row), 16B-chunk base (tid&3)*8
  const int srow = tid >> 2, scb = (tid & 3) * 8, ssw = srow & 7;
  const unsigned short* qwp = QW + (size_t)srow * HID + ks * 1024 + scb * 8;
  // B stream: this lane's s-row and k-phase
  const int s = stile * 64 + wv * 16 + l16;
  const unsigned short* bp = hsbf + ((size_t)b * SS + s) * HID + ks * 1024 + quad * 8;

  f32x4 acc[4] = {};
  for (int ck = 0; ck < 4; ++ck) {
    __syncthreads();
    #pragma unroll
    for (int j = 0; j < 8; ++j) {
      uint4 v = *(const uint4*)(qwp + ck * 256 + j * 8);
      *(uint4*)&Qs[srow * 256 + (((scb + j) ^ ssw) << 3)] = v;
    }
    __syncthreads();
    // issue all 8 B-frag loads for this chunk up front (independent, stay in flight)
    uint4 bf[8];
    #pragma unroll
    for (int ksub = 0; ksub < 8; ++ksub)
      bf[ksub] = *(const uint4*)(bp + ck * 256 + ksub * 32);
    #pragma unroll
    for (int ksub = 0; ksub < 8; ++ksub) {
      bf16x8 bfrag = __builtin_bit_cast(bf16x8, bf[ksub]);
      #pragma unroll
      for (int mt = 0; mt < 4; ++mt) {
        const int rr = mt * 16 + l16;
        const int c = ksub * 4 + quad;      // 16B-chunk index within 256-k row
        bf16x8 afrag = *(const bf16x8*)&Qs[rr * 256 + ((c ^ (rr & 7)) << 3)];
        acc[mt] = __builtin_amdgcn_mfma_f32_16x16x32_bf16(afrag, bfrag, acc[mt], 0, 0, 0);
      }
    }
  }
  // C layout: col(n=s)=l16 (fixed per lane), row(m=r)=quad*4+reg, m-tile offset mt*16
  #pragma unroll
  for (int mt = 0; mt < 4; ++mt)
    #pragma unroll
    for (int j = 0; j < 4; ++j)
      sp[(((size_t)ks * BB + b) * R64 + mt * 16 + quad * 4 + j) * SS + s] = acc[mt][j];
}

// ---- 4: softmax over s per (b,r): sum 4 K-partials, mask, bf16 attn out.
__global__ __launch_bounds__(256) void softmax_kernel(const float* __restrict__ sp,
                                                      const int* __restrict__ mask,
                                                      unsigned short* __restrict__ attn) {
  int br = blockIdx.x;            // b*64 + r
  int b = br >> 6;
  int tid = threadIdx.x;
  const int* mrow = mask + b * SS;
  const size_t kstride = (size_t)BB * R64 * SS;
  float vals[16];
  float mx = -INFINITY;
  #pragma unroll
  for (int j = 0; j < 16; ++j) {
    int s = tid + j * 256;
    size_t o = (size_t)br * SS + s;
    float v = sp[o] + sp[o + kstride] + sp[o + 2 * kstride] + sp[o + 3 * kstride];
    if (mrow[s] == 0) v = -INFINITY;
    vals[j] = v;
    mx = fmaxf(mx, v);
  }
  __shared__ float redm[4], reds[4];
  #pragma unroll
  for (int off = 32; off; off >>= 1) mx = fmaxf(mx, __shfl_down(mx, off, 64));
  if ((tid & 63) == 0) redm[tid >> 6] = mx;
  __syncthreads();
  mx = fmaxf(fmaxf(redm[0], redm[1]), fmaxf(redm[2], redm[3]));
  float sum = 0.f;
  #pragma unroll
  for (int j = 0; j < 16; ++j) { vals[j] = expf(vals[j] - mx); sum += vals[j]; }
  #pragma unroll
  for (int off = 32; off; off >>= 1) sum += __shfl_down(sum, off, 64);
  if ((tid & 63) == 0) reds[tid >> 6] = sum;
  __syncthreads();
  sum = reds[0] + reds[1] + reds[2] + reds[3];
  float inv = 1.f / sum;
  #pragma unroll
  for (int j = 0; j < 16; ++j)
    attn[(size_t)br * SS + tid + j * 256] = f2bf(vals[j] * inv);
}

// ---- 5: partial ctx cp[ss][b][r][i] = sum_{s-slice} attn[b][r][s]*hsbf[b][s][i]
// grid (64 itile, 4 ss, 4 b). Tile M=64(r) x N=64(i), K-slice=1024(s).
__global__ __launch_bounds__(256, 4) void ctx_mfma(const unsigned short* __restrict__ attn,
                                                   const unsigned short* __restrict__ hsbf,
                                                   float* __restrict__ cp) {
  __shared__ unsigned short As[64 * 64];  // [r][s] swizzled
  __shared__ unsigned short Bs[64 * 64];  // [i][s] swizzled (transposed hs tile)
  const int itile = blockIdx.x, ss = blockIdx.y, b = blockIdx.z;
  const int tid = threadIdx.x;
  const int wv = tid >> 6, lane = tid & 63;
  const int quad = lane >> 4, l16 = lane & 15;
  // A staging: thread -> (r row 0..63, 16 contiguous s); chunks 2*(tid&3), +1
  const int arow = tid >> 2, asc = (tid & 3) << 4;
  const int ch0 = (tid & 3) << 1, swa = arow & 7;
  const unsigned short* ap = attn + (size_t)(b * R64 + arow) * SS + ss * 1024 + asc;
  unsigned short* asw0 = &As[arow * 64 + (((ch0 + 0) ^ swa) << 3)];
  unsigned short* asw1 = &As[arow * 64 + (((ch0 + 1) ^ swa) << 3)];
  // B staging: thread -> s-pair p (rows 2p,2p+1), i-group g (8 cols at g*8)
  const int p = tid & 31, g = tid >> 5;
  const unsigned short* bp0 = hsbf + (size_t)(b * SS + ss * 1024 + 2 * p) * HID + itile * 64 + g * 8;
  const unsigned short* bp1 = bp0 + HID;

  f32x4 acc[4] = {};
  uint4 aa0 = *(const uint4*)(ap);
  uint4 aa1 = *(const uint4*)(ap + 8);
  uint4 hb0 = *(const uint4*)(bp0);
  uint4 hb1 = *(const uint4*)(bp1);

  for (int c = 0; c < 16; ++c) {
    __syncthreads();
    *(uint4*)asw0 = aa0;
    *(uint4*)asw1 = aa1;
    {
      unsigned int lo[4] = {hb0.x, hb0.y, hb0.z, hb0.w};
      unsigned int hi[4] = {hb1.x, hb1.y, hb1.z, hb1.w};
      #pragma unroll
      for (int t = 0; t < 4; ++t) {
        unsigned int d0 = (lo[t] & 0xffffu) | (hi[t] << 16);
        unsigned int d1 = (lo[t] >> 16) | (hi[t] & 0xffff0000u);
        int i0 = g * 8 + 2 * t, i1 = i0 + 1;
        ((unsigned int*)Bs)[i0 * 32 + (((p >> 2) ^ (i0 & 7)) << 2) + (p & 3)] = d0;
        ((unsigned int*)Bs)[i1 * 32 + (((p >> 2) ^ (i1 & 7)) << 2) + (p & 3)] = d1;
      }
    }
    __syncthreads();
    if (c < 15) {
      const unsigned short* an = ap + (size_t)(c + 1) * 64;
      aa0 = *(const uint4*)(an);
      aa1 = *(const uint4*)(an + 8);
      const unsigned short* bn0 = bp0 + (size_t)(c + 1) * 64 * HID;
      hb0 = *(const uint4*)(bn0);
      hb1 = *(const uint4*)(bn0 + HID);
    }
    #pragma unroll
    for (int kk = 0; kk < 2; ++kk) {
      const int nrow = wv * 16 + l16;
      bf16x8 bfrag = *(const bf16x8*)&Bs[nrow * 64 + (((kk * 4 + quad) ^ (nrow & 7)) << 3)];
      #pragma unroll
      for (int mt = 0; mt < 4; ++mt) {
        const int mrow = mt * 16 + l16;
        bf16x8 afrag = *(const bf16x8*)&As[mrow * 64 + (((kk * 4 + quad) ^ (mrow & 7)) << 3)];
        acc[mt] = __builtin_amdgcn_mfma_f32_16x16x32_bf16(afrag, bfrag, acc[mt], 0, 0, 0);
      }
    }
  }
  const int i = itile * 64 + wv * 16 + l16;
  #pragma unroll
  for (int mt = 0; mt < 4; ++mt) {
    int r0 = mt * 16 + quad * 4;
    #pragma unroll
    for (int j = 0; j < 4; ++j)
      cp[(((size_t)ss * BB + b) * R64 + r0 + j) * HID + i] = acc[mt][j];
  }
}

// ---- 6: out[b][n][h*64+d] = sum_i (sum_ss cp[ss][b][h*8+n][i]) * Wv[h*64+d][i]
__global__ void out_kernel(const float* __restrict__ cp, const float* __restrict__ Wv,
                           float* __restrict__ out) {
  int w = (blockIdx.x * blockDim.x + threadIdx.x) >> 6;
  int lane = threadIdx.x & 63;
  if (w >= BB * SLOTS * BD) return;   // 16384
  int b = w >> 12, n = (w >> 9) & 7, hd = w & 511, h = hd >> 6;
  const size_t sstride = (size_t)BB * R64 * HID;
  const float* c  = cp + ((size_t)b * R64 + h * 8 + n) * HID;
  const float* wv = Wv + (size_t)hd * HID;
  float acc = 0.f;
  for (int i = lane; i < HID; i += 64) {
    float s = c[i] + c[i + sstride] + c[i + 2 * sstride] + c[i + 3 * sstride];
    acc = fmaf(s, wv[i], acc);
  }
  #pragma unroll
  for (int off = 32; off; off >>= 1) acc += __shfl_down(acc, off, 64);
  if (lane == 0) out[w] = acc;
}

// ---- 7: y[b][n][o] = sum_d out[b][n][d] * Wo[o][d]
__global__ void final_kernel(const float* __restrict__ out, const float* __restrict__ Wo,
                             float* __restrict__ y) {
  int w = (blockIdx.x * blockDim.x + threadIdx.x) >> 6;
  int lane = threadIdx.x & 63;
  if (w >= BB * SLOTS * HID) return;  // 131072
  int bn = w >> 12, o = w & 4095;
  const float* orow = out + bn * BD;
  const float* wo = Wo + (size_t)o * BD;
  float acc = 0.f;
  #pragma unroll
  for (int d = lane; d < BD; d += 64) acc = fmaf(orow[d], wo[d], acc);
  #pragma unroll
  for (int off = 32; off; off >>= 1) acc += __shfl_down(acc, off, 64);
  if (lane == 0) y[w] = acc;
}

extern "C" void kernel_launch(void* const* d_in, const int* in_sizes, int n_in,
                              void* d_out, int out_size, void* d_ws, size_t ws_size,
                              hipStream_t stream) {
  const float* hs   = (const float*)d_in[0];
  const int*   mask = (const int*)d_in[1];
  const float* ms   = (const float*)d_in[2];
  const float* Wq   = (const float*)d_in[3];
  const float* Wk   = (const float*)d_in[4];
  const float* Wv   = (const float*)d_in[5];
  const float* Wo   = (const float*)d_in[6];

  // Workspace layout (~163 MB)
  char* ws = (char*)d_ws;
  float*          Q    = (float*)ws;          ws += 4096 * 4;                        // 16 KB
  unsigned short* QW   = (unsigned short*)ws; ws += (size_t)R64 * HID * 2;           // 512 KB
  float*          sp   = (float*)ws;          ws += (size_t)4 * BB * R64 * SS * 4;   // 16 MB
  unsigned short* attn = (unsigned short*)ws; ws += (size_t)BB * R64 * SS * 2;       // 2 MB
  float*          cp   = (float*)ws;          ws += (size_t)4 * BB * R64 * HID * 4;  // 16 MB
  unsigned short* hsbf = (unsigned short*)ws; ws += (size_t)BB * SS * HID * 2;       // 128 MB
  float*          out  = (float*)ws;                                                 // 64 KB

  cvt_kernel<<<dim3(4096), 256, 0, stream>>>((const float4*)hs, (uint2*)hsbf);
  q_kernel<<<dim3((SLOTS * BD * 64) / 256), 256, 0, stream>>>(ms, Wq, Q);
  qw_kernel<<<dim3((R64 * HID) / 256), 256, 0, stream>>>(Q, Wk, QW);
  scores_mfma<<<dim3(64, 4, 4), 256, 0, stream>>>(hsbf, QW, sp);
  softmax_kernel<<<dim3(BB * R64), 256, 0, stream>>>(sp, mask, attn);
  ctx_mfma<<<dim3(64, 4, 4), 256, 0, stream>>>(attn, hsbf, cp);
  out_kernel<<<dim3(4096), 256, 0, stream>>>(cp, Wv, out);
  final_kernel<<<dim3(32768), 256, 0, stream>>>(out, Wo, (float*)d_out);
}